// Round 9
// baseline (1134.257 us; speedup 1.0000x reference)
//
#include <hip/hip_runtime.h>
#include <hip/hip_bf16.h>

typedef __attribute__((ext_vector_type(8))) unsigned short u16x8;
typedef __attribute__((ext_vector_type(8))) short bf16x8;
typedef __attribute__((ext_vector_type(4))) float f32x4;

#define DEVI __device__ __forceinline__

constexpr int Bc = 16;
constexpr int Nc = 4096;
constexpr int Sc = 1024;   // NPOINT
constexpr int Kc = 32;
constexpr int Dc = 64;
constexpr int C1 = 67;
constexpr int Mtot = Bc * Sc * Kc;  // 524288
constexpr float EPSc = 1e-5f;
constexpr float CNTinv = 1.0f / (float)Mtot;
constexpr int NREP = 8;         // stats replicas (atomic-contention spread)
constexpr int REPSTRIDE = 512;  // floats per replica
constexpr int NB_FPS = Bc;
constexpr int NB_KNN = Bc * Sc / 4;   // 4096
constexpr int NB_CONV = Mtot / 64;    // 8192

// no-FMA squared distance, matches numpy (x*x + y*y) + z*z
DEVI float sqdist3(float dx, float dy, float dz) {
  return __fadd_rn(__fadd_rn(__fmul_rn(dx, dx), __fmul_rn(dy, dy)), __fmul_rn(dz, dz));
}
DEVI unsigned long long umax64(unsigned long long a, unsigned long long b) { return a > b ? a : b; }
DEVI float bf2f(unsigned short u) { return __uint_as_float(((unsigned)u) << 16); }
DEVI unsigned short f2bf(float f) {
  __hip_bfloat16 h = __float2bfloat16(f);
  unsigned short u;
  __builtin_memcpy(&u, &h, 2);
  return u;
}
DEVI unsigned pack_bf2(float a, float b) {
  return (unsigned)f2bf(a) | ((unsigned)f2bf(b) << 16);
}

// ---- wave64 DPP reductions ----
#define DPP_STAGE(v, OP, CTRL, MASK)                                                       \
  {                                                                                        \
    int _t = __builtin_amdgcn_update_dpp(__float_as_int(v), __float_as_int(v), CTRL, MASK, \
                                         0xF, false);                                      \
    v = OP(v, __int_as_float(_t));                                                         \
  }
DEVI float wave_fmax63(float v) {
  DPP_STAGE(v, fmaxf, 0xB1, 0xF)
  DPP_STAGE(v, fmaxf, 0x4E, 0xF)
  DPP_STAGE(v, fmaxf, 0x141, 0xF)
  DPP_STAGE(v, fmaxf, 0x140, 0xF)
  DPP_STAGE(v, fmaxf, 0x142, 0xA)
  DPP_STAGE(v, fmaxf, 0x143, 0xC)
  return __int_as_float(__builtin_amdgcn_readlane(__float_as_int(v), 63));
}
DEVI float wave_fmin63(float v) {
  DPP_STAGE(v, fminf, 0xB1, 0xF)
  DPP_STAGE(v, fminf, 0x4E, 0xF)
  DPP_STAGE(v, fminf, 0x141, 0xF)
  DPP_STAGE(v, fminf, 0x140, 0xF)
  DPP_STAGE(v, fminf, 0x142, 0xA)
  DPP_STAGE(v, fminf, 0x143, 0xC)
  return __int_as_float(__builtin_amdgcn_readlane(__float_as_int(v), 63));
}
#define DPP_STAGE_U(v, CTRL, MASK)                                                      \
  {                                                                                     \
    unsigned _t = (unsigned)__builtin_amdgcn_update_dpp((int)(v), (int)(v), CTRL, MASK, \
                                                        0xF, false);                    \
    v = (_t < v) ? _t : v;                                                              \
  }
DEVI unsigned wave_umin63(unsigned v) {
  DPP_STAGE_U(v, 0xB1, 0xF)
  DPP_STAGE_U(v, 0x4E, 0xF)
  DPP_STAGE_U(v, 0x141, 0xF)
  DPP_STAGE_U(v, 0x140, 0xF)
  DPP_STAGE_U(v, 0x142, 0xA)
  DPP_STAGE_U(v, 0x143, 0xC)
  return (unsigned)__builtin_amdgcn_readlane((int)v, 63);
}

struct FpsS {
  float4 lsc[Nc];  // 64 KiB coord table (b128 centroid reads)
  int sidx[Sc];
  unsigned long long wkey[2][4];
};
struct ConvS {
  float feats[C1][68];
  float Wt[C1][64];
  float red1[4][16][8];
};
union SmemU {
  FpsS f;
  ConvS c;
};

// ================= mega kernel: [fps 16][knn 4096][conv1 8192] =================
__global__ __launch_bounds__(256) void mega_kernel(
    const float* __restrict__ xyz, const float* __restrict__ points,
    const float* __restrict__ W1, const float* __restrict__ b1,
    int* fidx, int* idx, int* qdone, float* statsOut,
    __hip_bfloat16* __restrict__ x1, float* out) {
  __shared__ SmemU sm;
  __shared__ float cent2[2][3];
  const int bid = blockIdx.x;
  const int tid = threadIdx.x;
  const int lane = tid & 63, w = tid >> 6;

  if (bid < NB_FPS) {
    // ---------------- FPS role (r4-verified body, float4 LDS, high prio) ----------------
    __builtin_amdgcn_s_setprio(3);
    const int b = bid;
    const float* xb = xyz + (size_t)b * Nc * 3;
    float px[16], py[16], pz[16], dist[16];
#pragma unroll
    for (int i = 0; i < 16; ++i) {
      int p = tid + i * 256;
      px[i] = xb[p * 3 + 0];
      py[i] = xb[p * 3 + 1];
      pz[i] = xb[p * 3 + 2];
      dist[i] = 1e10f;
    }
    for (int e = tid; e < Nc; e += 256)
      sm.f.lsc[e] = make_float4(xb[e * 3 + 0], xb[e * 3 + 1], xb[e * 3 + 2], 0.f);
    if (tid == 0) atomicExch(&fidx[b * Sc], 0);
    __syncthreads();

    int widx = 0;
    for (int t = 1; t < Sc; ++t) {
      const float4 c = sm.f.lsc[widx];
      float nd[16];
#pragma unroll
      for (int i = 0; i < 16; ++i) {
        float d = sqdist3(px[i] - c.x, py[i] - c.y, pz[i] - c.z);
        float v = fminf(dist[i], d);
        dist[i] = v;
        nd[i] = v;
      }
      float t8[8], t4[4];
#pragma unroll
      for (int u = 0; u < 8; ++u) t8[u] = fmaxf(nd[u], nd[u + 8]);
#pragma unroll
      for (int u = 0; u < 4; ++u) t4[u] = fmaxf(t8[u], t8[u + 4]);
      const float mymax = fmaxf(fmaxf(t4[0], t4[1]), fmaxf(t4[2], t4[3]));
      const float maxw = wave_fmax63(mymax);
      unsigned lp = 0xFFFFFFFFu;
#pragma unroll
      for (int i = 15; i >= 0; --i) lp = (nd[i] == maxw) ? (unsigned)(tid + (i << 8)) : lp;
      const unsigned long long mask = __ballot(mymax == maxw);
      unsigned wavep;
      if (__builtin_popcountll(mask) == 1) {
        wavep = (unsigned)__builtin_amdgcn_readlane((int)lp, (int)__builtin_ctzll(mask));
      } else {
        wavep = wave_umin63(lp);  // exact smallest-index tie-break (rare)
      }
      if (lane == 0)
        sm.f.wkey[t & 1][w] = ((unsigned long long)__float_as_uint(maxw) << 32) |
                              (unsigned long long)(0xFFFFFFFFu - wavep);
      __syncthreads();
      const ulonglong2* wp = (const ulonglong2*)sm.f.wkey[t & 1];
      ulonglong2 a0 = wp[0], a1 = wp[1];
      unsigned long long m = umax64(umax64(a0.x, a0.y), umax64(a1.x, a1.y));
      widx = (int)(0xFFFFFFFFu - (unsigned)(m & 0xFFFFFFFFu));
      if (tid == 0) {
        sm.f.sidx[t] = widx;
        if ((t & 7) == 0 || t == Sc - 1) {  // batched publish
          int base = t - ((t - 1) & 7);
          for (int u = base; u <= t; ++u) atomicExch(&fidx[b * Sc + u], sm.f.sidx[u]);
        }
      }
    }
    return;
  }

  if (bid < NB_FPS + NB_KNN) {
    // ---------------- kNN role (top-4 cache, r7-verified) ----------------
    const int q = (bid - NB_FPS) * 4 + w;
    const int b = q >> 10;
    const int s = q & (Sc - 1);
    const float* xb = xyz + (size_t)b * Nc * 3;
    int ci = -1;
    if (lane == 0) {
      while ((ci = atomicAdd(&fidx[b * Sc + s], 0)) < 0) __builtin_amdgcn_s_sleep(32);
    }
    ci = __shfl(ci, 0, 64);
    const float cx = xb[ci * 3 + 0], cy = xb[ci * 3 + 1], cz = xb[ci * 3 + 2];
    if (lane == 0) {
      atomicExch(&out[(b * Sc + s) * 3 + 0], cx);
      atomicExch(&out[(b * Sc + s) * 3 + 1], cy);
      atomicExch(&out[(b * Sc + s) * 3 + 2], cz);
    }
    const float INF = __int_as_float(0x7F800000);
    const float* pp = xb + lane * 3;
    float d0 = INF, d1 = INF, d2 = INF, d3 = INF;
    int i0 = 0, i1 = 0, i2 = 0, i3 = 0;
#pragma unroll 4
    for (int i = 0; i < 64; ++i) {
      const float x = pp[i * 192 + 0], y = pp[i * 192 + 1], z = pp[i * 192 + 2];
      const float d = sqdist3(x - cx, y - cy, z - cz);
      const bool c0 = d < d0, c1 = d < d1, c2 = d < d2, c3 = d < d3;
      d3 = c2 ? d2 : (c3 ? d : d3);
      i3 = c2 ? i2 : (c3 ? i : i3);
      d2 = c1 ? d1 : (c2 ? d : d2);
      i2 = c1 ? i1 : (c2 ? i : i2);
      d1 = c0 ? d0 : (c1 ? d : d1);
      i1 = c0 ? i0 : (c1 ? i : i1);
      d0 = c0 ? d : d0;
      i0 = c0 ? i : i0;
    }
    unsigned long long taken = 0ull;
    int* outp = idx + ((size_t)b * Sc + s) * Kc;
#pragma unroll 1
    for (int r = 0; r < Kc; ++r) {
      const float mind = wave_fmin63(d0);
      const unsigned myp = (unsigned)(lane + (i0 << 6));
      const unsigned long long mask = __ballot(d0 == mind);
      unsigned W;
      if (__builtin_popcountll(mask) == 1) {
        W = (unsigned)__builtin_amdgcn_readlane((int)myp, (int)__builtin_ctzll(mask));
      } else {
        unsigned c = (d0 == mind) ? myp : 0xFFFFFFFFu;
        W = wave_umin63(c);
      }
      if (lane == 0) atomicExch(&outp[r], (int)W);
      if (myp == W) {
        taken |= (1ull << i0);
        d0 = d1; i0 = i1;
        d1 = d2; i1 = i2;
        d2 = d3; i2 = i3;
        d3 = INF;
        if (__float_as_uint(d0) == 0x7F800000u) {
          float e0 = INF, e1 = INF, e2 = INF, e3 = INF;
          int j0 = 0, j1 = 0, j2 = 0, j3 = 0;
#pragma unroll 4
          for (int i = 0; i < 64; ++i) {
            const float x = pp[i * 192 + 0], y = pp[i * 192 + 1], z = pp[i * 192 + 2];
            float d = sqdist3(x - cx, y - cy, z - cz);
            d = ((taken >> i) & 1ull) ? INF : d;
            const bool c0b = d < e0, c1b = d < e1, c2b = d < e2, c3b = d < e3;
            e3 = c2b ? e2 : (c3b ? d : e3);
            j3 = c2b ? j2 : (c3b ? i : j3);
            e2 = c1b ? e1 : (c2b ? d : e2);
            j2 = c1b ? j1 : (c2b ? i : j2);
            e1 = c0b ? e0 : (c1b ? d : e1);
            j1 = c0b ? j0 : (c1b ? i : j1);
            e0 = c0b ? d : e0;
            j0 = c0b ? i : j0;
          }
          d0 = e0; i0 = j0; d1 = e1; i1 = j1; d2 = e2; i2 = j2; d3 = e3; i3 = j3;
        }
      }
    }
    if (lane == 0) {
      __threadfence();           // order idx atomics before the flag
      atomicExch(&qdone[q], 1);  // release flag
    }
    return;
  }

  // ---------------- conv1 role (gather + 67->64 fp32 conv + fused stats) ----------------
  {
    const int cb = bid - NB_FPS - NB_KNN;
    const int m0 = cb * 64;
    for (int e = tid; e < 64 * C1; e += 256) {  // stage W1 while waiting
      int c = e / C1, j = e % C1;
      sm.c.Wt[j][c] = W1[e];
    }
    if (tid == 0 || tid == 64) {
      const int qq = (cb << 1) + (tid >> 6);
      while (atomicAdd(&qdone[qq], 0) == 0) __builtin_amdgcn_s_sleep(32);
      // recompute centroid coords from fidx (atomic) + xyz: bit-identical to knn's write,
      // avoids stale-L1 risk on the atomic-written out[] buffer
      const int bq = qq >> 10, sq = qq & (Sc - 1);
      const int ciq = atomicAdd(&fidx[bq * Sc + sq], 0);
      const float* cpq = xyz + ((size_t)bq * Nc + ciq) * 3;
      cent2[tid >> 6][0] = cpq[0];
      cent2[tid >> 6][1] = cpq[1];
      cent2[tid >> 6][2] = cpq[2];
    }
    __syncthreads();
    {
      const int p = tid >> 2, qd = tid & 3;
      const int m = m0 + p;
      const int b = m >> 15;
      int i;
      {
        int tmp = 0;
        if (qd == 0) tmp = atomicAdd(&idx[m], 0);  // coherent read of knn's atomic write
        i = __shfl(tmp, lane & ~3, 64);
      }
      const float* pr = points + ((size_t)b * Nc + i) * Dc + qd * 16;
      float4 v0 = *(const float4*)(pr + 0);
      float4 v1 = *(const float4*)(pr + 4);
      float4 v2 = *(const float4*)(pr + 8);
      float4 v3 = *(const float4*)(pr + 12);
      float vv[16] = {v0.x, v0.y, v0.z, v0.w, v1.x, v1.y, v1.z, v1.w,
                      v2.x, v2.y, v2.z, v2.w, v3.x, v3.y, v3.z, v3.w};
      const int j0 = 3 + qd * 16;
#pragma unroll
      for (int u = 0; u < 16; ++u) sm.c.feats[j0 + u][p] = vv[u];
      if (qd == 0) {
        const float* xp = xyz + ((size_t)b * Nc + i) * 3;
        sm.c.feats[0][p] = xp[0] - cent2[p >> 5][0];
        sm.c.feats[1][p] = xp[1] - cent2[p >> 5][1];
        sm.c.feats[2][p] = xp[2] - cent2[p >> 5][2];
      }
    }
    __syncthreads();
    const int c0 = (tid & 15) * 4, p0 = (tid >> 4) * 4;
    float acc[4][4];
#pragma unroll
    for (int cc = 0; cc < 4; ++cc) {
      float bb = b1[c0 + cc];
#pragma unroll
      for (int pp = 0; pp < 4; ++pp) acc[pp][cc] = bb;
    }
#pragma unroll 4
    for (int j = 0; j < C1; ++j) {
      const float4 f = *(const float4*)&sm.c.feats[j][p0];
      const float4 wv = *(const float4*)&sm.c.Wt[j][c0];
      const float fa[4] = {f.x, f.y, f.z, f.w};
      const float wa[4] = {wv.x, wv.y, wv.z, wv.w};
#pragma unroll
      for (int pp = 0; pp < 4; ++pp)
#pragma unroll
        for (int cc = 0; cc < 4; ++cc) acc[pp][cc] = fmaf(fa[pp], wa[cc], acc[pp][cc]);
    }
    float s_[4] = {0.f, 0.f, 0.f, 0.f}, q_[4] = {0.f, 0.f, 0.f, 0.f};
#pragma unroll
    for (int pp = 0; pp < 4; ++pp) {
      unsigned short hv[4];
#pragma unroll
      for (int cc = 0; cc < 4; ++cc) {
        hv[cc] = f2bf(acc[pp][cc]);
        float fr = bf2f(hv[cc]);
        s_[cc] += fr;
        q_[cc] += fr * fr;
      }
      unsigned r0 = (unsigned)hv[0] | ((unsigned)hv[1] << 16);
      unsigned r1 = (unsigned)hv[2] | ((unsigned)hv[3] << 16);
      unsigned short* dst = (unsigned short*)x1 + (size_t)(m0 + p0 + pp) * 64 + c0;
      *(uint2*)dst = make_uint2(r0, r1);
    }
#pragma unroll
    for (int cc = 0; cc < 4; ++cc) {
      s_[cc] += __shfl_xor(s_[cc], 16, 64);
      s_[cc] += __shfl_xor(s_[cc], 32, 64);
      q_[cc] += __shfl_xor(q_[cc], 16, 64);
      q_[cc] += __shfl_xor(q_[cc], 32, 64);
    }
    if (lane < 16) {
#pragma unroll
      for (int cc = 0; cc < 4; ++cc) {
        sm.c.red1[w][lane][cc] = s_[cc];
        sm.c.red1[w][lane][4 + cc] = q_[cc];
      }
    }
    __syncthreads();
    if (tid < 128) {
      int h = tid >> 6, ch = tid & 63;
      int g = ch >> 2, cc = ch & 3;
      float v = sm.c.red1[0][g][h * 4 + cc] + sm.c.red1[1][g][h * 4 + cc] +
                sm.c.red1[2][g][h * 4 + cc] + sm.c.red1[3][g][h * 4 + cc];
      atomicAdd(&statsOut[(cb & (NREP - 1)) * REPSTRIDE + h * 64 + ch], v);
    }
  }
}

// ---------------- convN (MFMA): BN+ReLU -> bf16 LDS (swizzled), 16x16x32 MFMA,
//                  fused next-layer stats; LAST also fuses per-(s,ch) min/max ----------------
template <int COUT, bool LAST>
__global__ __launch_bounds__(256) void convm_kernel(
    const __hip_bfloat16* __restrict__ xin, const float* __restrict__ statsIn,
    const float* __restrict__ gamma, const float* __restrict__ beta,
    const float* __restrict__ W, const float* __restrict__ bias,
    float* __restrict__ statsOut, __hip_bfloat16* __restrict__ xout,
    unsigned* __restrict__ ymm) {
  constexpr int NT = COUT / 16;
  __shared__ __align__(16) unsigned short fA[64 * 64];     // swizzled bf16 activations
  __shared__ __align__(16) unsigned short fW[COUT * 64];   // swizzled bf16 weights
  __shared__ float scs[64], shs[64];
  __shared__ float red[4][COUT][2];
  __shared__ float redmm[LAST ? 4 : 1][COUT][2];
  __shared__ unsigned short fStage[64][72];
  const int tid = threadIdx.x;
  const int lane = tid & 63, w = tid >> 6;
  const long m0 = (long)blockIdx.x * 64;

  if (tid < 64) {
    float s0 = 0.f, s1 = 0.f;
#pragma unroll
    for (int r = 0; r < NREP; ++r) {
      s0 += statsIn[r * REPSTRIDE + tid];
      s1 += statsIn[r * REPSTRIDE + 64 + tid];
    }
    float mean = s0 * CNTinv;
    float var = s1 * CNTinv - mean * mean;
    float sc = gamma[tid] * rsqrtf(var + EPSc);
    scs[tid] = sc;
    shs[tid] = beta[tid] - mean * sc;
  }
  for (int e = tid; e < COUT * 64; e += 256) {
    int r = e >> 6, k = e & 63;
    int byte = (k * 2) ^ ((r & 7) << 4);
    fW[r * 64 + (byte >> 1)] = f2bf(W[e]);
  }
  __syncthreads();
  {
    const int row = tid >> 2, cb = tid & 3;
    const unsigned short* src = (const unsigned short*)xin + (m0 + row) * 64 + cb * 16;
    u16x8 a = *(const u16x8*)src;
    u16x8 bv = *(const u16x8*)(src + 8);
    unsigned short o[16];
#pragma unroll
    for (int u = 0; u < 8; ++u) {
      int ch = cb * 16 + u;
      o[u] = f2bf(fmaxf(fmaf(scs[ch], bf2f(a[u]), shs[ch]), 0.f));
    }
#pragma unroll
    for (int u = 0; u < 8; ++u) {
      int ch = cb * 16 + 8 + u;
      o[8 + u] = f2bf(fmaxf(fmaf(scs[ch], bf2f(bv[u]), shs[ch]), 0.f));
    }
    int sw = (row & 7) << 4;
    *(bf16x8*)((char*)fA + row * 128 + ((cb * 32) ^ sw)) = *(bf16x8*)&o[0];
    *(bf16x8*)((char*)fA + row * 128 + ((cb * 32 + 16) ^ sw)) = *(bf16x8*)&o[8];
  }
  __syncthreads();

  const int fr = lane & 15, kchunk = lane >> 4;
  f32x4 acc[NT];
#pragma unroll
  for (int nt = 0; nt < NT; ++nt) {
    float bb = bias[nt * 16 + fr];
    acc[nt] = f32x4{bb, bb, bb, bb};
  }
  bf16x8 af0, af1;
  {
    int row = w * 16 + fr;
    int sw = (row & 7) << 4;
    af0 = *(bf16x8*)((char*)fA + row * 128 + ((kchunk * 16) ^ sw));
    af1 = *(bf16x8*)((char*)fA + row * 128 + ((64 + kchunk * 16) ^ sw));
  }
#pragma unroll
  for (int nt = 0; nt < NT; ++nt) {
    int r2 = nt * 16 + fr;
    int sw = (r2 & 7) << 4;
    bf16x8 bf0 = *(bf16x8*)((char*)fW + r2 * 128 + ((kchunk * 16) ^ sw));
    bf16x8 bf1 = *(bf16x8*)((char*)fW + r2 * 128 + ((64 + kchunk * 16) ^ sw));
    acc[nt] = __builtin_amdgcn_mfma_f32_16x16x32_bf16(af0, bf0, acc[nt], 0, 0, 0);
    acc[nt] = __builtin_amdgcn_mfma_f32_16x16x32_bf16(af1, bf1, acc[nt], 0, 0, 0);
  }

  float s_[NT], q_[NT], mn_[NT], mx_[NT];
#pragma unroll
  for (int nt = 0; nt < NT; ++nt) {
    s_[nt] = 0.f;
    q_[nt] = 0.f;
    mn_[nt] = 1e30f;
    mx_[nt] = -1e30f;
    unsigned short hv[4];
#pragma unroll
    for (int r = 0; r < 4; ++r) {
      hv[r] = f2bf(acc[nt][r]);
      float fr2 = bf2f(hv[r]);
      s_[nt] += fr2;
      q_[nt] += fr2 * fr2;
      if constexpr (LAST) {
        mn_[nt] = fminf(mn_[nt], fr2);
        mx_[nt] = fmaxf(mx_[nt], fr2);
      }
    }
    if constexpr (!LAST) {
#pragma unroll
      for (int r = 0; r < 4; ++r) fStage[w * 16 + kchunk * 4 + r][nt * 16 + fr] = hv[r];
    }
  }
#pragma unroll
  for (int nt = 0; nt < NT; ++nt) {
    s_[nt] += __shfl_xor(s_[nt], 16, 64);
    s_[nt] += __shfl_xor(s_[nt], 32, 64);
    q_[nt] += __shfl_xor(q_[nt], 16, 64);
    q_[nt] += __shfl_xor(q_[nt], 32, 64);
    if constexpr (LAST) {
      mn_[nt] = fminf(mn_[nt], __shfl_xor(mn_[nt], 16, 64));
      mn_[nt] = fminf(mn_[nt], __shfl_xor(mn_[nt], 32, 64));
      mx_[nt] = fmaxf(mx_[nt], __shfl_xor(mx_[nt], 16, 64));
      mx_[nt] = fmaxf(mx_[nt], __shfl_xor(mx_[nt], 32, 64));
    }
  }
  if (lane < 16) {
#pragma unroll
    for (int nt = 0; nt < NT; ++nt) {
      red[w][nt * 16 + lane][0] = s_[nt];
      red[w][nt * 16 + lane][1] = q_[nt];
      if constexpr (LAST) {
        redmm[w][nt * 16 + lane][0] = mn_[nt];
        redmm[w][nt * 16 + lane][1] = mx_[nt];
      }
    }
  }
  __syncthreads();
  if (tid < 2 * COUT) {
    int ch = tid >> 1, h = tid & 1;
    float v = red[0][ch][h] + red[1][ch][h] + red[2][ch][h] + red[3][ch][h];
    atomicAdd(&statsOut[((int)blockIdx.x & (NREP - 1)) * REPSTRIDE + h * COUT + ch], v);
  }
  if constexpr (LAST) {
    int sg = tid >> 7, ch = tid & 127;
    float mn = fminf(redmm[sg * 2][ch][0], redmm[sg * 2 + 1][ch][0]);
    float mx = fmaxf(redmm[sg * 2][ch][1], redmm[sg * 2 + 1][ch][1]);
    ymm[(size_t)(m0 / 32 + sg) * 128 + ch] = pack_bf2(mn, mx);
  } else {
    int row = tid >> 2, cb = tid & 3;
    unsigned short* dst = (unsigned short*)xout + (m0 + row) * 64 + cb * 16;
    *(uint4*)dst = *(uint4*)&fStage[row][cb * 16];
    *(uint4*)(dst + 8) = *(uint4*)&fStage[row][cb * 16 + 8];
  }
}

// ---------------- pool: BN3 on per-(s,ch) min/max + ReLU, write [B,128,S] ----------------
__global__ __launch_bounds__(256) void pool_kernel(const unsigned* __restrict__ ymm,
                                                   const float* __restrict__ stats,
                                                   const float* __restrict__ gamma,
                                                   const float* __restrict__ beta,
                                                   float* __restrict__ out) {
  __shared__ float sc[128], sh[128];
  __shared__ float res[128][33];
  const int tid = threadIdx.x;
  if (tid < 128) {
    float s0 = 0.f, s1 = 0.f;
#pragma unroll
    for (int r = 0; r < NREP; ++r) {
      s0 += stats[r * REPSTRIDE + tid];
      s1 += stats[r * REPSTRIDE + 128 + tid];
    }
    float mean = s0 * CNTinv;
    float var = s1 * CNTinv - mean * mean;
    float s = gamma[tid] * rsqrtf(var + EPSc);
    sc[tid] = s;
    sh[tid] = beta[tid] - mean * s;
  }
  __syncthreads();
  const int b = blockIdx.x >> 5;
  const int s0 = (blockIdx.x & 31) * 32;
  const int w = tid >> 6, lane = tid & 63;
  const int c0 = lane * 2;
  const float sc0 = sc[c0], sh0 = sh[c0], sc1 = sc[c0 + 1], sh1 = sh[c0 + 1];
  for (int si = 0; si < 8; ++si) {
    const int s = s0 + w * 8 + si;
    uint2 v = *(const uint2*)&ymm[(size_t)(b * Sc + s) * 128 + c0];
    float f0 = (sc0 >= 0.f) ? bf2f((unsigned short)(v.x >> 16)) : bf2f((unsigned short)(v.x & 0xFFFFu));
    float f1 = (sc1 >= 0.f) ? bf2f((unsigned short)(v.y >> 16)) : bf2f((unsigned short)(v.y & 0xFFFFu));
    res[c0][s - s0] = fmaxf(fmaf(sc0, f0, sh0), 0.f);
    res[c0 + 1][s - s0] = fmaxf(fmaf(sc1, f1, sh1), 0.f);
  }
  __syncthreads();
  const int c = tid >> 1, h = tid & 1;
  float* ob = out + (size_t)b * 128 * Sc + (size_t)c * Sc + s0 + h * 16;
#pragma unroll
  for (int u = 0; u < 16; ++u) ob[u] = res[c][h * 16 + u];
}

extern "C" void kernel_launch(void* const* d_in, const int* in_sizes, int n_in,
                              void* d_out, int out_size, void* d_ws, size_t ws_size,
                              hipStream_t stream) {
  const float* xyz = (const float*)d_in[0];
  const float* points = (const float*)d_in[1];
  const float* W1 = (const float*)d_in[2];
  const float* b1 = (const float*)d_in[3];
  const float* g1 = (const float*)d_in[4];
  const float* bt1 = (const float*)d_in[5];
  const float* W2 = (const float*)d_in[6];
  const float* b2 = (const float*)d_in[7];
  const float* g2 = (const float*)d_in[8];
  const float* bt2 = (const float*)d_in[9];
  const float* W3 = (const float*)d_in[10];
  const float* b3 = (const float*)d_in[11];
  const float* g3 = (const float*)d_in[12];
  const float* bt3 = (const float*)d_in[13];
  float* out = (float*)d_out;

  char* ws = (char*)d_ws;
  // layout: fidx[64K] | idx[2M] | stats[16K] | qdone[64K] | x1[67M] | x2[67M] | ymm[8M]
  int* fidx = (int*)(ws + 0);
  int* idx = (int*)(ws + 65536);
  float* stats = (float*)(ws + 2162688);
  int* qdone = (int*)(ws + 2179072);
  __hip_bfloat16* x1 = (__hip_bfloat16*)(ws + 2244608);
  __hip_bfloat16* x2 = (__hip_bfloat16*)(ws + 2244608 + 67108864);
  unsigned* ymm = (unsigned*)(ws + 2244608 + 134217728);

  hipMemsetAsync(stats, 0, NREP * REPSTRIDE * sizeof(float), stream);
  hipMemsetAsync(fidx, 0xFF, Bc * Sc * sizeof(int), stream);  // -1 sentinel
  hipMemsetAsync(qdone, 0, Bc * Sc * sizeof(int), stream);
  mega_kernel<<<NB_FPS + NB_KNN + NB_CONV, 256, 0, stream>>>(xyz, points, W1, b1, fidx, idx,
                                                             qdone, stats, x1, out);
  convm_kernel<64, false><<<Mtot / 64, 256, 0, stream>>>(x1, stats, g1, bt1, W2, b2,
                                                         stats + 128, x2, nullptr);
  convm_kernel<128, true><<<Mtot / 64, 256, 0, stream>>>(x2, stats + 128, g2, bt2, W3, b3,
                                                         stats + 256, nullptr, ymm);
  pool_kernel<<<Bc * (Sc / 32), 256, 0, stream>>>(ymm, stats + 256, g3, bt3,
                                                  out + Bc * Sc * 3);
}

// Round 10
// 993.352 us; speedup vs baseline: 1.1418x; 1.1418x over previous
//
#include <hip/hip_runtime.h>
#include <hip/hip_bf16.h>

typedef __attribute__((ext_vector_type(8))) unsigned short u16x8;
typedef __attribute__((ext_vector_type(8))) short bf16x8;
typedef __attribute__((ext_vector_type(4))) float f32x4;

#define DEVI __device__ __forceinline__

constexpr int Bc = 16;
constexpr int Nc = 4096;
constexpr int Sc = 1024;   // NPOINT
constexpr int Kc = 32;
constexpr int Dc = 64;
constexpr int C1 = 67;
constexpr int Mtot = Bc * Sc * Kc;  // 524288
constexpr float EPSc = 1e-5f;
constexpr float CNTinv = 1.0f / (float)Mtot;
constexpr int NREP = 8;         // stats replicas (atomic-contention spread)
constexpr int REPSTRIDE = 512;  // floats per replica

// no-FMA squared distance, matches numpy (x*x + y*y) + z*z
DEVI float sqdist3(float dx, float dy, float dz) {
  return __fadd_rn(__fadd_rn(__fmul_rn(dx, dx), __fmul_rn(dy, dy)), __fmul_rn(dz, dz));
}
DEVI unsigned long long umax64(unsigned long long a, unsigned long long b) { return a > b ? a : b; }
DEVI float bf2f(unsigned short u) { return __uint_as_float(((unsigned)u) << 16); }
DEVI unsigned short f2bf(float f) {
  __hip_bfloat16 h = __float2bfloat16(f);
  unsigned short u;
  __builtin_memcpy(&u, &h, 2);
  return u;
}
DEVI unsigned pack_bf2(float a, float b) {
  return (unsigned)f2bf(a) | ((unsigned)f2bf(b) << 16);
}

// ---- wave64 DPP reductions ----
#define DPP_STAGE(v, OP, CTRL, MASK)                                                       \
  {                                                                                        \
    int _t = __builtin_amdgcn_update_dpp(__float_as_int(v), __float_as_int(v), CTRL, MASK, \
                                         0xF, false);                                      \
    v = OP(v, __int_as_float(_t));                                                         \
  }
DEVI float wave_fmax63(float v) {
  DPP_STAGE(v, fmaxf, 0xB1, 0xF)
  DPP_STAGE(v, fmaxf, 0x4E, 0xF)
  DPP_STAGE(v, fmaxf, 0x141, 0xF)
  DPP_STAGE(v, fmaxf, 0x140, 0xF)
  DPP_STAGE(v, fmaxf, 0x142, 0xA)
  DPP_STAGE(v, fmaxf, 0x143, 0xC)
  return __int_as_float(__builtin_amdgcn_readlane(__float_as_int(v), 63));
}
DEVI float wave_fmin63(float v) {
  DPP_STAGE(v, fminf, 0xB1, 0xF)
  DPP_STAGE(v, fminf, 0x4E, 0xF)
  DPP_STAGE(v, fminf, 0x141, 0xF)
  DPP_STAGE(v, fminf, 0x140, 0xF)
  DPP_STAGE(v, fminf, 0x142, 0xA)
  DPP_STAGE(v, fminf, 0x143, 0xC)
  return __int_as_float(__builtin_amdgcn_readlane(__float_as_int(v), 63));
}
#define DPP_STAGE_U(v, CTRL, MASK)                                                      \
  {                                                                                     \
    unsigned _t = (unsigned)__builtin_amdgcn_update_dpp((int)(v), (int)(v), CTRL, MASK, \
                                                        0xF, false);                    \
    v = (_t < v) ? _t : v;                                                              \
  }
DEVI unsigned wave_umin63(unsigned v) {
  DPP_STAGE_U(v, 0xB1, 0xF)
  DPP_STAGE_U(v, 0x4E, 0xF)
  DPP_STAGE_U(v, 0x141, 0xF)
  DPP_STAGE_U(v, 0x140, 0xF)
  DPP_STAGE_U(v, 0x142, 0xA)
  DPP_STAGE_U(v, 0x143, 0xC)
  return (unsigned)__builtin_amdgcn_readlane((int)v, 63);
}

// ---------------- FPS: 256 thr (4 waves), ballot+readlane winner, 1 barrier/step ----------------
// (r4/r6 version, counter-verified 680-683 us)
__global__ __launch_bounds__(256) void fps_kernel(const float* __restrict__ xyz,
                                                  int* __restrict__ fidx) {
  __shared__ float4 lsc[Nc];  // 64 KiB coord table (read-only in loop)
  __shared__ __align__(16) unsigned long long wkey[2][4];
  __shared__ int sidx[Sc];
  const int b = blockIdx.x;
  const float* xb = xyz + (size_t)b * Nc * 3;
  const int tid = threadIdx.x;
  const int lane = tid & 63, w = tid >> 6;

  float px[16], py[16], pz[16], dist[16];
#pragma unroll
  for (int i = 0; i < 16; ++i) {
    int p = tid + i * 256;
    px[i] = xb[p * 3 + 0];
    py[i] = xb[p * 3 + 1];
    pz[i] = xb[p * 3 + 2];
    dist[i] = 1e10f;
  }
  for (int e = tid; e < Nc; e += 256)
    lsc[e] = make_float4(xb[e * 3 + 0], xb[e * 3 + 1], xb[e * 3 + 2], 0.f);
  if (tid == 0) sidx[0] = 0;
  __syncthreads();

  int widx = 0;
  for (int t = 1; t < Sc; ++t) {
    const float4 c = lsc[widx];
    float nd[16];
#pragma unroll
    for (int i = 0; i < 16; ++i) {
      float d = sqdist3(px[i] - c.x, py[i] - c.y, pz[i] - c.z);
      float v = fminf(dist[i], d);
      dist[i] = v;
      nd[i] = v;
    }
    // depth-4 tree max over this lane's 16 updated distances
    float t8[8], t4[4];
#pragma unroll
    for (int u = 0; u < 8; ++u) t8[u] = fmaxf(nd[u], nd[u + 8]);
#pragma unroll
    for (int u = 0; u < 4; ++u) t4[u] = fmaxf(t8[u], t8[u + 4]);
    const float mymax = fmaxf(fmaxf(t4[0], t4[1]), fmaxf(t4[2], t4[3]));
    const float maxw = wave_fmax63(mymax);  // wave max, broadcast
    // smallest local point index with nd == maxw (reverse scan -> smallest i wins)
    unsigned lp = 0xFFFFFFFFu;
#pragma unroll
    for (int i = 15; i >= 0; --i) lp = (nd[i] == maxw) ? (unsigned)(tid + (i << 8)) : lp;
    const unsigned long long mask = __ballot(mymax == maxw);
    unsigned wavep;
    if (__builtin_popcountll(mask) == 1) {
      wavep = (unsigned)__builtin_amdgcn_readlane((int)lp, (int)__builtin_ctzll(mask));
    } else {
      wavep = wave_umin63(lp);  // exact smallest-index tie-break (rare)
    }
    if (lane == 0)
      wkey[t & 1][w] = ((unsigned long long)__float_as_uint(maxw) << 32) |
                       (unsigned long long)(0xFFFFFFFFu - wavep);
    __syncthreads();
    const ulonglong2* wp = (const ulonglong2*)wkey[t & 1];
    ulonglong2 a0 = wp[0], a1 = wp[1];
    unsigned long long m = umax64(umax64(a0.x, a0.y), umax64(a1.x, a1.y));
    widx = (int)(0xFFFFFFFFu - (unsigned)(m & 0xFFFFFFFFu));
    if (tid == 0) sidx[t] = widx;
  }
  __syncthreads();
  for (int e = tid; e < Sc; e += 256) fidx[b * Sc + e] = sidx[e];
}

// ---------------- kNN: one wave/query, top-4 cache + taken mask, ballot argmin ----------------
// (r7 version, counter-verified)
__global__ __launch_bounds__(256) void knn_kernel(const float* __restrict__ xyz,
                                                  const int* __restrict__ fidx,
                                                  float* __restrict__ new_xyz,
                                                  int* __restrict__ idx) {
  const int w = threadIdx.x >> 6;
  const int lane = threadIdx.x & 63;
  const int q = blockIdx.x * 4 + w;
  const int b = q >> 10;
  const int s = q & (Sc - 1);
  const float* xb = xyz + (size_t)b * Nc * 3;
  const int ci = fidx[b * Sc + s];
  const float cx = xb[ci * 3 + 0], cy = xb[ci * 3 + 1], cz = xb[ci * 3 + 2];
  if (lane == 0) {
    new_xyz[(b * Sc + s) * 3 + 0] = cx;
    new_xyz[(b * Sc + s) * 3 + 1] = cy;
    new_xyz[(b * Sc + s) * 3 + 2] = cz;
  }
  const float INF = __int_as_float(0x7F800000);
  // lane owns points p = lane + 64*i, i in [0,64)
  const float* pp = xb + lane * 3;
  float d0 = INF, d1 = INF, d2 = INF, d3 = INF;
  int i0 = 0, i1 = 0, i2 = 0, i3 = 0;
#pragma unroll 4
  for (int i = 0; i < 64; ++i) {
    const float x = pp[i * 192 + 0], y = pp[i * 192 + 1], z = pp[i * 192 + 2];
    const float d = sqdist3(x - cx, y - cy, z - cz);
    const bool c0 = d < d0, c1 = d < d1, c2 = d < d2, c3 = d < d3;  // strict <: stable
    d3 = c2 ? d2 : (c3 ? d : d3);
    i3 = c2 ? i2 : (c3 ? i : i3);
    d2 = c1 ? d1 : (c2 ? d : d2);
    i2 = c1 ? i1 : (c2 ? i : i2);
    d1 = c0 ? d0 : (c1 ? d : d1);
    i1 = c0 ? i0 : (c1 ? i : i1);
    d0 = c0 ? d : d0;
    i0 = c0 ? i : i0;
  }
  unsigned long long taken = 0ull;
  int* outp = idx + ((size_t)b * Sc + s) * Kc;
#pragma unroll 1
  for (int r = 0; r < Kc; ++r) {
    const float mind = wave_fmin63(d0);
    const unsigned myp = (unsigned)(lane + (i0 << 6));
    const unsigned long long mask = __ballot(d0 == mind);
    unsigned W;
    if (__builtin_popcountll(mask) == 1) {
      W = (unsigned)__builtin_amdgcn_readlane((int)myp, (int)__builtin_ctzll(mask));
    } else {
      unsigned c = (d0 == mind) ? myp : 0xFFFFFFFFu;
      W = wave_umin63(c);  // exact (dist, idx) lexicographic argmin (rare ties)
    }
    if (lane == 0) outp[r] = (int)W;
    if (myp == W) {  // unique winner lane
      taken |= (1ull << i0);
      d0 = d1; i0 = i1;
      d1 = d2; i1 = i2;
      d2 = d3; i2 = i3;
      d3 = INF;
      if (__float_as_uint(d0) == 0x7F800000u) {  // cache exhausted -> rebuild top-4
        float e0 = INF, e1 = INF, e2 = INF, e3 = INF;
        int j0 = 0, j1 = 0, j2 = 0, j3 = 0;
#pragma unroll 4
        for (int i = 0; i < 64; ++i) {
          const float x = pp[i * 192 + 0], y = pp[i * 192 + 1], z = pp[i * 192 + 2];
          float d = sqdist3(x - cx, y - cy, z - cz);
          d = ((taken >> i) & 1ull) ? INF : d;
          const bool c0b = d < e0, c1b = d < e1, c2b = d < e2, c3b = d < e3;
          e3 = c2b ? e2 : (c3b ? d : e3);
          j3 = c2b ? j2 : (c3b ? i : j3);
          e2 = c1b ? e1 : (c2b ? d : e2);
          j2 = c1b ? j1 : (c2b ? i : j2);
          e1 = c0b ? e0 : (c1b ? d : e1);
          j1 = c0b ? j0 : (c1b ? i : j1);
          e0 = c0b ? d : e0;
          j0 = c0b ? i : j0;
        }
        d0 = e0; i0 = j0; d1 = e1; i1 = j1; d2 = e2; i2 = j2; d3 = e3; i3 = j3;
      }
    }
  }
}

// ---------------- conv1: gather + 67->64 conv (fp32 VALU) + fused layer-1 stats ----------------
__global__ __launch_bounds__(256) void conv1_kernel(
    const float* __restrict__ xyz, const float* __restrict__ points,
    const float* __restrict__ new_xyz, const int* __restrict__ idx,
    const float* __restrict__ W1, const float* __restrict__ b1,
    __hip_bfloat16* __restrict__ x1, float* __restrict__ statsOut) {
  __shared__ float feats[C1][68];
  __shared__ float Wt[C1][64];
  __shared__ float red1[4][16][8];
  const int tid = threadIdx.x;
  const int lane = tid & 63, w = tid >> 6;
  const int m0 = blockIdx.x * 64;
  for (int e = tid; e < 64 * C1; e += 256) {
    int c = e / C1, j = e % C1;
    Wt[j][c] = W1[e];
  }
  {
    const int p = tid >> 2, qd = tid & 3;
    const int m = m0 + p;
    const int b = m >> 15;
    const int s = (m >> 5) & (Sc - 1);
    const int i = idx[m];
    const float* pr = points + ((size_t)b * Nc + i) * Dc + qd * 16;
    float4 v0 = *(const float4*)(pr + 0);
    float4 v1 = *(const float4*)(pr + 4);
    float4 v2 = *(const float4*)(pr + 8);
    float4 v3 = *(const float4*)(pr + 12);
    float vv[16] = {v0.x, v0.y, v0.z, v0.w, v1.x, v1.y, v1.z, v1.w,
                    v2.x, v2.y, v2.z, v2.w, v3.x, v3.y, v3.z, v3.w};
    const int j0 = 3 + qd * 16;
#pragma unroll
    for (int u = 0; u < 16; ++u) feats[j0 + u][p] = vv[u];
    if (qd == 0) {
      const float* xp = xyz + ((size_t)b * Nc + i) * 3;
      const float* cp = new_xyz + ((size_t)b * Sc + s) * 3;
      feats[0][p] = xp[0] - cp[0];
      feats[1][p] = xp[1] - cp[1];
      feats[2][p] = xp[2] - cp[2];
    }
  }
  __syncthreads();
  const int c0 = (tid & 15) * 4, p0 = (tid >> 4) * 4;
  float acc[4][4];
#pragma unroll
  for (int cc = 0; cc < 4; ++cc) {
    float bb = b1[c0 + cc];
#pragma unroll
    for (int pp = 0; pp < 4; ++pp) acc[pp][cc] = bb;
  }
#pragma unroll 4
  for (int j = 0; j < C1; ++j) {
    const float4 f = *(const float4*)&feats[j][p0];
    const float4 wv = *(const float4*)&Wt[j][c0];
    const float fa[4] = {f.x, f.y, f.z, f.w};
    const float wa[4] = {wv.x, wv.y, wv.z, wv.w};
#pragma unroll
    for (int pp = 0; pp < 4; ++pp)
#pragma unroll
      for (int cc = 0; cc < 4; ++cc) acc[pp][cc] = fmaf(fa[pp], wa[cc], acc[pp][cc]);
  }
  float s_[4] = {0.f, 0.f, 0.f, 0.f}, q_[4] = {0.f, 0.f, 0.f, 0.f};
#pragma unroll
  for (int pp = 0; pp < 4; ++pp) {
    unsigned short hv[4];
#pragma unroll
    for (int cc = 0; cc < 4; ++cc) {
      hv[cc] = f2bf(acc[pp][cc]);
      float fr = bf2f(hv[cc]);
      s_[cc] += fr;
      q_[cc] += fr * fr;
    }
    unsigned r0 = (unsigned)hv[0] | ((unsigned)hv[1] << 16);
    unsigned r1 = (unsigned)hv[2] | ((unsigned)hv[3] << 16);
    unsigned short* dst = (unsigned short*)x1 + (size_t)(m0 + p0 + pp) * 64 + c0;
    *(uint2*)dst = make_uint2(r0, r1);
  }
#pragma unroll
  for (int cc = 0; cc < 4; ++cc) {
    s_[cc] += __shfl_xor(s_[cc], 16, 64);
    s_[cc] += __shfl_xor(s_[cc], 32, 64);
    q_[cc] += __shfl_xor(q_[cc], 16, 64);
    q_[cc] += __shfl_xor(q_[cc], 32, 64);
  }
  if (lane < 16) {
#pragma unroll
    for (int cc = 0; cc < 4; ++cc) {
      red1[w][lane][cc] = s_[cc];
      red1[w][lane][4 + cc] = q_[cc];
    }
  }
  __syncthreads();
  if (tid < 128) {
    int h = tid >> 6, ch = tid & 63;
    int g = ch >> 2, cc = ch & 3;
    float v = red1[0][g][h * 4 + cc] + red1[1][g][h * 4 + cc] + red1[2][g][h * 4 + cc] +
              red1[3][g][h * 4 + cc];
    atomicAdd(&statsOut[(blockIdx.x & (NREP - 1)) * REPSTRIDE + h * 64 + ch], v);
  }
}

// ---------------- convN (MFMA): BN+ReLU -> bf16 LDS (swizzled), 16x16x32 MFMA,
//                  fused next-layer stats; LAST also fuses per-(s,ch) min/max ----------------
template <int COUT, bool LAST>
__global__ __launch_bounds__(256) void convm_kernel(
    const __hip_bfloat16* __restrict__ xin, const float* __restrict__ statsIn,
    const float* __restrict__ gamma, const float* __restrict__ beta,
    const float* __restrict__ W, const float* __restrict__ bias,
    float* __restrict__ statsOut, __hip_bfloat16* __restrict__ xout,
    unsigned* __restrict__ ymm) {
  constexpr int NT = COUT / 16;
  __shared__ __align__(16) unsigned short fA[64 * 64];     // swizzled bf16 activations
  __shared__ __align__(16) unsigned short fW[COUT * 64];   // swizzled bf16 weights
  __shared__ float scs[64], shs[64];
  __shared__ float red[4][COUT][2];
  __shared__ float redmm[LAST ? 4 : 1][COUT][2];
  __shared__ unsigned short fStage[64][72];
  const int tid = threadIdx.x;
  const int lane = tid & 63, w = tid >> 6;
  const long m0 = (long)blockIdx.x * 64;

  if (tid < 64) {
    float s0 = 0.f, s1 = 0.f;
#pragma unroll
    for (int r = 0; r < NREP; ++r) {
      s0 += statsIn[r * REPSTRIDE + tid];
      s1 += statsIn[r * REPSTRIDE + 64 + tid];
    }
    float mean = s0 * CNTinv;
    float var = s1 * CNTinv - mean * mean;
    float sc = gamma[tid] * rsqrtf(var + EPSc);
    scs[tid] = sc;
    shs[tid] = beta[tid] - mean * sc;
  }
  for (int e = tid; e < COUT * 64; e += 256) {
    int r = e >> 6, k = e & 63;
    int byte = (k * 2) ^ ((r & 7) << 4);
    fW[r * 64 + (byte >> 1)] = f2bf(W[e]);
  }
  __syncthreads();
  {
    const int row = tid >> 2, cb = tid & 3;
    const unsigned short* src = (const unsigned short*)xin + (m0 + row) * 64 + cb * 16;
    u16x8 a = *(const u16x8*)src;
    u16x8 bv = *(const u16x8*)(src + 8);
    unsigned short o[16];
#pragma unroll
    for (int u = 0; u < 8; ++u) {
      int ch = cb * 16 + u;
      o[u] = f2bf(fmaxf(fmaf(scs[ch], bf2f(a[u]), shs[ch]), 0.f));
    }
#pragma unroll
    for (int u = 0; u < 8; ++u) {
      int ch = cb * 16 + 8 + u;
      o[8 + u] = f2bf(fmaxf(fmaf(scs[ch], bf2f(bv[u]), shs[ch]), 0.f));
    }
    int sw = (row & 7) << 4;
    *(bf16x8*)((char*)fA + row * 128 + ((cb * 32) ^ sw)) = *(bf16x8*)&o[0];
    *(bf16x8*)((char*)fA + row * 128 + ((cb * 32 + 16) ^ sw)) = *(bf16x8*)&o[8];
  }
  __syncthreads();

  const int fr = lane & 15, kchunk = lane >> 4;
  f32x4 acc[NT];
#pragma unroll
  for (int nt = 0; nt < NT; ++nt) {
    float bb = bias[nt * 16 + fr];
    acc[nt] = f32x4{bb, bb, bb, bb};
  }
  bf16x8 af0, af1;
  {
    int row = w * 16 + fr;
    int sw = (row & 7) << 4;
    af0 = *(bf16x8*)((char*)fA + row * 128 + ((kchunk * 16) ^ sw));
    af1 = *(bf16x8*)((char*)fA + row * 128 + ((64 + kchunk * 16) ^ sw));
  }
#pragma unroll
  for (int nt = 0; nt < NT; ++nt) {
    int r2 = nt * 16 + fr;
    int sw = (r2 & 7) << 4;
    bf16x8 bf0 = *(bf16x8*)((char*)fW + r2 * 128 + ((kchunk * 16) ^ sw));
    bf16x8 bf1 = *(bf16x8*)((char*)fW + r2 * 128 + ((64 + kchunk * 16) ^ sw));
    acc[nt] = __builtin_amdgcn_mfma_f32_16x16x32_bf16(af0, bf0, acc[nt], 0, 0, 0);
    acc[nt] = __builtin_amdgcn_mfma_f32_16x16x32_bf16(af1, bf1, acc[nt], 0, 0, 0);
  }

  float s_[NT], q_[NT], mn_[NT], mx_[NT];
#pragma unroll
  for (int nt = 0; nt < NT; ++nt) {
    s_[nt] = 0.f;
    q_[nt] = 0.f;
    mn_[nt] = 1e30f;
    mx_[nt] = -1e30f;
    unsigned short hv[4];
#pragma unroll
    for (int r = 0; r < 4; ++r) {
      hv[r] = f2bf(acc[nt][r]);
      float fr2 = bf2f(hv[r]);
      s_[nt] += fr2;
      q_[nt] += fr2 * fr2;
      if constexpr (LAST) {
        mn_[nt] = fminf(mn_[nt], fr2);
        mx_[nt] = fmaxf(mx_[nt], fr2);
      }
    }
    if constexpr (!LAST) {
#pragma unroll
      for (int r = 0; r < 4; ++r) fStage[w * 16 + kchunk * 4 + r][nt * 16 + fr] = hv[r];
    }
  }
#pragma unroll
  for (int nt = 0; nt < NT; ++nt) {
    s_[nt] += __shfl_xor(s_[nt], 16, 64);
    s_[nt] += __shfl_xor(s_[nt], 32, 64);
    q_[nt] += __shfl_xor(q_[nt], 16, 64);
    q_[nt] += __shfl_xor(q_[nt], 32, 64);
    if constexpr (LAST) {
      mn_[nt] = fminf(mn_[nt], __shfl_xor(mn_[nt], 16, 64));
      mn_[nt] = fminf(mn_[nt], __shfl_xor(mn_[nt], 32, 64));
      mx_[nt] = fmaxf(mx_[nt], __shfl_xor(mx_[nt], 16, 64));
      mx_[nt] = fmaxf(mx_[nt], __shfl_xor(mx_[nt], 32, 64));
    }
  }
  if (lane < 16) {
#pragma unroll
    for (int nt = 0; nt < NT; ++nt) {
      red[w][nt * 16 + lane][0] = s_[nt];
      red[w][nt * 16 + lane][1] = q_[nt];
      if constexpr (LAST) {
        redmm[w][nt * 16 + lane][0] = mn_[nt];
        redmm[w][nt * 16 + lane][1] = mx_[nt];
      }
    }
  }
  __syncthreads();
  if (tid < 2 * COUT) {
    int ch = tid >> 1, h = tid & 1;
    float v = red[0][ch][h] + red[1][ch][h] + red[2][ch][h] + red[3][ch][h];
    atomicAdd(&statsOut[((int)blockIdx.x & (NREP - 1)) * REPSTRIDE + h * COUT + ch], v);
  }
  if constexpr (LAST) {
    // waves 0,1 hold rows 0-31 (s-group 0); waves 2,3 rows 32-63 (s-group 1)
    int sg = tid >> 7, ch = tid & 127;
    float mn = fminf(redmm[sg * 2][ch][0], redmm[sg * 2 + 1][ch][0]);
    float mx = fmaxf(redmm[sg * 2][ch][1], redmm[sg * 2 + 1][ch][1]);
    ymm[(size_t)(m0 / 32 + sg) * 128 + ch] = pack_bf2(mn, mx);
  } else {
    int row = tid >> 2, cb = tid & 3;
    unsigned short* dst = (unsigned short*)xout + (m0 + row) * 64 + cb * 16;
    *(uint4*)dst = *(uint4*)&fStage[row][cb * 16];
    *(uint4*)(dst + 8) = *(uint4*)&fStage[row][cb * 16 + 8];
  }
}

// ---------------- pool: BN3 on per-(s,ch) min/max + ReLU, write [B,128,S] ----------------
__global__ __launch_bounds__(256) void pool_kernel(const unsigned* __restrict__ ymm,
                                                   const float* __restrict__ stats,
                                                   const float* __restrict__ gamma,
                                                   const float* __restrict__ beta,
                                                   float* __restrict__ out) {
  __shared__ float sc[128], sh[128];
  __shared__ float res[128][33];
  const int tid = threadIdx.x;
  if (tid < 128) {
    float s0 = 0.f, s1 = 0.f;
#pragma unroll
    for (int r = 0; r < NREP; ++r) {
      s0 += stats[r * REPSTRIDE + tid];
      s1 += stats[r * REPSTRIDE + 128 + tid];
    }
    float mean = s0 * CNTinv;
    float var = s1 * CNTinv - mean * mean;
    float s = gamma[tid] * rsqrtf(var + EPSc);
    sc[tid] = s;
    sh[tid] = beta[tid] - mean * s;
  }
  __syncthreads();
  const int b = blockIdx.x >> 5;
  const int s0 = (blockIdx.x & 31) * 32;
  const int w = tid >> 6, lane = tid & 63;
  const int c0 = lane * 2;
  const float sc0 = sc[c0], sh0 = sh[c0], sc1 = sc[c0 + 1], sh1 = sh[c0 + 1];
  for (int si = 0; si < 8; ++si) {
    const int s = s0 + w * 8 + si;
    uint2 v = *(const uint2*)&ymm[(size_t)(b * Sc + s) * 128 + c0];
    float f0 = (sc0 >= 0.f) ? bf2f((unsigned short)(v.x >> 16)) : bf2f((unsigned short)(v.x & 0xFFFFu));
    float f1 = (sc1 >= 0.f) ? bf2f((unsigned short)(v.y >> 16)) : bf2f((unsigned short)(v.y & 0xFFFFu));
    res[c0][s - s0] = fmaxf(fmaf(sc0, f0, sh0), 0.f);
    res[c0 + 1][s - s0] = fmaxf(fmaf(sc1, f1, sh1), 0.f);
  }
  __syncthreads();
  const int c = tid >> 1, h = tid & 1;
  float* ob = out + (size_t)b * 128 * Sc + (size_t)c * Sc + s0 + h * 16;
#pragma unroll
  for (int u = 0; u < 16; ++u) ob[u] = res[c][h * 16 + u];
}

extern "C" void kernel_launch(void* const* d_in, const int* in_sizes, int n_in,
                              void* d_out, int out_size, void* d_ws, size_t ws_size,
                              hipStream_t stream) {
  const float* xyz = (const float*)d_in[0];
  const float* points = (const float*)d_in[1];
  const float* W1 = (const float*)d_in[2];
  const float* b1 = (const float*)d_in[3];
  const float* g1 = (const float*)d_in[4];
  const float* bt1 = (const float*)d_in[5];
  const float* W2 = (const float*)d_in[6];
  const float* b2 = (const float*)d_in[7];
  const float* g2 = (const float*)d_in[8];
  const float* bt2 = (const float*)d_in[9];
  const float* W3 = (const float*)d_in[10];
  const float* b3 = (const float*)d_in[11];
  const float* g3 = (const float*)d_in[12];
  const float* bt3 = (const float*)d_in[13];
  float* out = (float*)d_out;

  char* ws = (char*)d_ws;
  // layout: fidx[64KB] | idx[2MB] | stats[8 reps x 512 f32 = 16KB] | x1[67MB] | x2[67MB] | ymm[8MB]
  int* fidx = (int*)(ws + 0);
  int* idx = (int*)(ws + 65536);
  float* stats = (float*)(ws + 2162688);
  __hip_bfloat16* x1 = (__hip_bfloat16*)(ws + 2162688 + 16384);
  __hip_bfloat16* x2 = (__hip_bfloat16*)(ws + 2162688 + 16384 + 67108864);
  unsigned* ymm = (unsigned*)(ws + 2162688 + 16384 + 134217728);

  hipMemsetAsync(stats, 0, NREP * REPSTRIDE * sizeof(float), stream);
  fps_kernel<<<Bc, 256, 0, stream>>>(xyz, fidx);
  knn_kernel<<<Bc * Sc / 4, 256, 0, stream>>>(xyz, fidx, out, idx);
  conv1_kernel<<<Mtot / 64, 256, 0, stream>>>(xyz, points, out, idx, W1, b1, x1, stats);
  convm_kernel<64, false><<<Mtot / 64, 256, 0, stream>>>(x1, stats, g1, bt1, W2, b2,
                                                         stats + 128, x2, nullptr);
  convm_kernel<128, true><<<Mtot / 64, 256, 0, stream>>>(x2, stats + 128, g2, bt2, W3, b3,
                                                         stats + 256, nullptr, ymm);
  pool_kernel<<<Bc * (Sc / 32), 256, 0, stream>>>(ymm, stats + 256, g3, bt3,
                                                  out + Bc * Sc * 3);
}